// Round 7
// baseline (25902.859 us; speedup 1.0000x reference)
//
#include <hip/hip_runtime.h>
#include <hip/hip_bf16.h>
#include <hip/hip_cooperative_groups.h>

namespace cg = cooperative_groups;

using s16x8 = __attribute__((ext_vector_type(8))) short;   // 8 bf16 (4 VGPRs) MFMA frag
using f32x4 = __attribute__((ext_vector_type(4))) float;   // MFMA accumulator

constexpr int BB = 64;    // batch
constexpr int SS = 512;   // seq len
constexpr int II = 1024;  // input dim
constexpr int HH = 1024;  // hidden dim

__device__ __forceinline__ unsigned short f2bf(float f) {
  unsigned u = __float_as_uint(f);
  unsigned r = u + 0x7fffu + ((u >> 16) & 1u);   // RN-even
  return (unsigned short)(r >> 16);
}
__device__ __forceinline__ float bf2f(unsigned short h) {
  return __uint_as_float(((unsigned)h) << 16);
}

// ---------------------------------------------------------------------------
// W in MFMA-linear fragment order: Wpk[blk 256][hl 2][ks 2][kb 32][lane 64][e 8]
// ---------------------------------------------------------------------------
__global__ void __launch_bounds__(256) pack_w_lin(
    const float* __restrict__ wii, const float* __restrict__ whi_,
    const float* __restrict__ wif, const float* __restrict__ whf,
    const float* __restrict__ wig, const float* __restrict__ whg,
    const float* __restrict__ wio, const float* __restrict__ who,
    unsigned short* __restrict__ Wpk)
{
  unsigned f = blockIdx.x * 256 + threadIdx.x;   // frag id, 0..2097151
  int lane = f & 63;
  int kb   = (f >> 6) & 31;
  int ks   = (f >> 11) & 1;
  int hl   = (f >> 12) & 1;
  int blk  = (int)(f >> 13);
  int n = lane & 15, u = lane >> 4;
  int hc = blk * 4 + (n >> 2), g = n & 3;
  int k  = kb * 32 + u * 8;
  const float* wi4[4] = {wii, wif, wig, wio};
  const float* wh4[4] = {whi_, whf, whg, who};
  const float* src = (ks == 0) ? (wi4[g] + (size_t)hc * 1024 + k)
                               : (wh4[g] + (size_t)hc * 1024 + k);
  float4 v0 = *(const float4*)src;
  float4 v1 = *(const float4*)(src + 4);
  float vv[8] = {v0.x, v0.y, v0.z, v0.w, v1.x, v1.y, v1.z, v1.w};
  s16x8 r;
#pragma unroll
  for (int e = 0; e < 8; ++e) {
    unsigned short h = f2bf(vv[e]);
    r[e] = hl ? (short)f2bf(vv[e] - bf2f(h))   // residual split removes W-quant err
              : (short)h;
  }
  *(s16x8*)(Wpk + (size_t)f * 8) = r;
}

__global__ void __launch_bounds__(256) pack_bias(
    const float* __restrict__ bii, const float* __restrict__ bhi,
    const float* __restrict__ bif, const float* __restrict__ bhf,
    const float* __restrict__ big, const float* __restrict__ bhg,
    const float* __restrict__ bio, const float* __restrict__ bho,
    float* __restrict__ biasC)
{
  int cidx = blockIdx.x * 256 + threadIdx.x;  // 0..4095
  int col = cidx & 15, blk = cidx >> 4;
  int hc = blk * 4 + (col >> 2), g = col & 3;
  const float* bi4[4] = {bii, bif, big, bio};
  const float* bh4[4] = {bhi, bhf, bhg, bho};
  biasC[cidx] = bi4[g][hc] + bh4[g][hc];
}

// x [B][S][I] fp32 -> xb [S][B][I] bf16
__global__ void __launch_bounds__(256) conv_x(const float* __restrict__ x,
                                              unsigned short* __restrict__ xb)
{
  int bs = blockIdx.x;
  int b = bs >> 9, s = bs & 511;
  float4 v = *(const float4*)(x + ((size_t)b * 512 + s) * 1024 + threadIdx.x * 4);
  *(ushort4*)(xb + ((size_t)s * 64 + b) * 1024 + threadIdx.x * 4) =
      make_ushort4(f2bf(v.x), f2bf(v.y), f2bf(v.z), f2bf(v.w));
}

// hseq [S+1][B][H] bf16 -> out hidden_seq [B][S][H] fp32
__global__ void __launch_bounds__(256) conv_out(const unsigned short* __restrict__ hseq,
                                                float* __restrict__ out)
{
  int bt = blockIdx.x;             // 0..32767
  int b = bt >> 9, t = bt & 511;
  ushort4 v = *(const ushort4*)(hseq + (size_t)(t + 1) * 65536 + b * 1024 + threadIdx.x * 4);
  float4 o;
  o.x = bf2f(v.x); o.y = bf2f(v.y); o.z = bf2f(v.z); o.w = bf2f(v.w);
  *(float4*)(out + ((size_t)b * 512 + t) * 1024 + threadIdx.x * 4) = o;
}

// ---------------------------------------------------------------------------
// Hierarchical monotone barrier (r4). cnt lines 0..7 per-group arrival,
// line 8 global. Monotone counts, no resets.
// ---------------------------------------------------------------------------
__device__ __forceinline__ void hbar_arrive(int* cnt, int blk, int kbar) {
  int g = blk & 7;
  int* lp = cnt + g * 16;
  __hip_atomic_fetch_add(lp, 1, __ATOMIC_RELAXED, __HIP_MEMORY_SCOPE_AGENT);
  if (blk < 8) {   // master of group g == blk
    while (__hip_atomic_load(lp, __ATOMIC_RELAXED, __HIP_MEMORY_SCOPE_AGENT) < 32 * kbar)
      __builtin_amdgcn_s_sleep(1);
    __hip_atomic_fetch_add(cnt + 8 * 16, 1, __ATOMIC_RELAXED, __HIP_MEMORY_SCOPE_AGENT);
  }
}
__device__ __forceinline__ void hbar_spin(int* cnt, int kbar) {
  int* gp = cnt + 8 * 16;
  while (__hip_atomic_load(gp, __ATOMIC_RELAXED, __HIP_MEMORY_SCOPE_AGENT) < 8 * kbar)
    __builtin_amdgcn_s_sleep(1);
}

// bf16 K=1024 GEMM half: A from global, W from LDS (MFMA-linear frag order).
__device__ __forceinline__ void gemm_pf(const unsigned short* __restrict__ aptr,
                                        const s16x8* __restrict__ WlV, int wbase,
                                        f32x4& outH, f32x4& outL) {
  s16x8 a[32];
#pragma unroll
  for (int kb = 0; kb < 32; ++kb) a[kb] = *(const s16x8*)(aptr + kb * 32);
  f32x4 h0 = {0.f, 0.f, 0.f, 0.f}, h1 = h0, l0 = h0, l1 = h0;
#pragma unroll
  for (int kb = 0; kb < 32; kb += 2) {
    s16x8 bh0 = WlV[wbase + kb * 64];
    s16x8 bl0 = WlV[4096 + wbase + kb * 64];
    s16x8 bh1 = WlV[wbase + (kb + 1) * 64];
    s16x8 bl1 = WlV[4096 + wbase + (kb + 1) * 64];
    h0 = __builtin_amdgcn_mfma_f32_16x16x32_bf16(a[kb],     bh0, h0, 0, 0, 0);
    l0 = __builtin_amdgcn_mfma_f32_16x16x32_bf16(a[kb],     bl0, l0, 0, 0, 0);
    h1 = __builtin_amdgcn_mfma_f32_16x16x32_bf16(a[kb + 1], bh1, h1, 0, 0, 0);
    l1 = __builtin_amdgcn_mfma_f32_16x16x32_bf16(a[kb + 1], bl1, l1, 0, 0, 0);
  }
  outH = h0 + h1;
  outL = l0 + l1;
}

// fp32-x fallback variant
__device__ __forceinline__ void gemm_f32x(const float* __restrict__ xp,
                                          const s16x8* __restrict__ WlV, int wbase,
                                          f32x4& outH, f32x4& outL) {
  f32x4 h0 = {0.f, 0.f, 0.f, 0.f}, l0 = h0;
#pragma unroll
  for (int kb = 0; kb < 32; ++kb) {
    float4 f0 = *(const float4*)(xp + kb * 32);
    float4 f1 = *(const float4*)(xp + kb * 32 + 4);
    s16x8 a;
    a[0] = (short)f2bf(f0.x); a[1] = (short)f2bf(f0.y);
    a[2] = (short)f2bf(f0.z); a[3] = (short)f2bf(f0.w);
    a[4] = (short)f2bf(f1.x); a[5] = (short)f2bf(f1.y);
    a[6] = (short)f2bf(f1.z); a[7] = (short)f2bf(f1.w);
    s16x8 bh = WlV[wbase + kb * 64];
    s16x8 bl = WlV[4096 + wbase + kb * 64];
    h0 = __builtin_amdgcn_mfma_f32_16x16x32_bf16(a, bh, h0, 0, 0, 0);
    l0 = __builtin_amdgcn_mfma_f32_16x16x32_bf16(a, bl, l0, 0, 0, 0);
  }
  outH = h0;
  outL = l0;
}

// ---------------------------------------------------------------------------
// Functional persistent LSTM — EXACT r4 structure (best measured: 5556 us).
// ---------------------------------------------------------------------------
template <bool USE_XB>
__global__ void __launch_bounds__(512, 1) lstm_fast3(
    const unsigned short* __restrict__ Wpk,  // [256][2][2][32][64][8] bf16
    const float* __restrict__ biasC,         // [256][16]
    const unsigned short* __restrict__ xb,   // [S][B][I] bf16 (USE_XB)
    const float* __restrict__ xin,           // [B][S][I] fp32 (!USE_XB)
    unsigned short* __restrict__ hseq,       // [S+1][B][H] bf16 rotating
    int* __restrict__ cnt,                   // 9 lines x 64B, monotone
    const float* __restrict__ h0,
    const float* __restrict__ c0,
    float* __restrict__ out)                 // [hidden_seq][h_f][c_f]
{
  __shared__ s16x8 WlV[8192];                // 128 KB, MFMA-linear frags
  __shared__ float gLds[2][64][17];          // K-half partials, padded
  __shared__ float biasLds[16];
  __shared__ short hOutLds[64][4];           // staged h_{t+1} for 8B flush

  const int tid  = threadIdx.x;
  const int blk  = blockIdx.x;
  const int wave = tid >> 6, lane = tid & 63;
  const int ks = wave >> 2;       // 0: x waves (0-3), 1: h waves (4-7)
  const int m  = wave & 3;        // batch tile
  const int arow = m * 16 + (lane & 15);
  const int koff = (lane >> 4) * 8;
  const int wbase = ks * 2048 + lane;

  {
    const s16x8* src = (const s16x8*)(Wpk + (size_t)blk * 65536);
#pragma unroll
    for (int it = 0; it < 16; ++it) WlV[it * 512 + tid] = src[it * 512 + tid];
  }
  if (tid < 16) biasLds[tid] = biasC[blk * 16 + tid];

  if (tid < 128) {
    int p = blk * 128 + tid;                 // pair index over B*H/2
    unsigned lo = f2bf(h0[2 * p]), hi = f2bf(h0[2 * p + 1]);
    __hip_atomic_store((unsigned*)(hseq + 2 * p), lo | (hi << 16),
                       __ATOMIC_RELAXED, __HIP_MEMORY_SCOPE_AGENT);
  }
  const int rb_batch = tid >> 2, rb_j = tid & 3;
  float c_reg = 0.f;
  if (tid < 256) c_reg = c0[rb_batch * 1024 + blk * 4 + rb_j];

  __syncthreads();                           // W staged; h0 stores drained

  f32x4 xaccH = {0.f, 0.f, 0.f, 0.f}, xaccL = xaccH;

  if (ks == 0) {
    if (USE_XB) gemm_pf(xb + arow * 1024 + koff, WlV, wbase, xaccH, xaccL);
    else        gemm_f32x(xin + (size_t)arow * 512 * 1024 + koff, WlV, wbase, xaccH, xaccL);
  }
  if (tid == 256) { hbar_arrive(cnt, blk, 1); hbar_spin(cnt, 1); }
  __syncthreads();

  for (int t = 0; t < SS; ++t) {
    // ---- phase A ----
    if (ks == 1) {
      f32x4 pH, pL;
      gemm_pf(hseq + (size_t)t * 65536 + arow * 1024 + koff, WlV, wbase, pH, pL);
      f32x4 acc = pH + pL;
      int drow = m * 16 + (lane >> 4) * 4;
      int dcol = lane & 15;
#pragma unroll
      for (int r = 0; r < 4; ++r) gLds[1][drow + r][dcol] = acc[r];
    } else {
      f32x4 acc = xaccH + xaccL;
      int drow = m * 16 + (lane >> 4) * 4;
      int dcol = lane & 15;
#pragma unroll
      for (int r = 0; r < 4; ++r) gLds[0][drow + r][dcol] = acc[r];
      if (t + 1 < SS) {
        if (USE_XB) gemm_pf(xb + (size_t)(t + 1) * 65536 + arow * 1024 + koff,
                            WlV, wbase, xaccH, xaccL);
        else        gemm_f32x(xin + ((size_t)arow * 512 + (t + 1)) * 1024 + koff,
                              WlV, wbase, xaccH, xaccL);
      }
    }
    __syncthreads();

    // ---- phase B: gate math ----
    if (tid < 256) {
      int c0i = rb_j * 4;
      float si = gLds[0][rb_batch][c0i + 0] + gLds[1][rb_batch][c0i + 0] + biasLds[c0i + 0];
      float sf = gLds[0][rb_batch][c0i + 1] + gLds[1][rb_batch][c0i + 1] + biasLds[c0i + 1];
      float sg = gLds[0][rb_batch][c0i + 2] + gLds[1][rb_batch][c0i + 2] + biasLds[c0i + 2];
      float so = gLds[0][rb_batch][c0i + 3] + gLds[1][rb_batch][c0i + 3] + biasLds[c0i + 3];
      float iv = 1.f / (1.f + __expf(-si));
      float fv = 1.f / (1.f + __expf(-sf));
      float gv = tanhf(sg);
      float ov = 1.f / (1.f + __expf(-so));
      c_reg = fv * c_reg + iv * gv;
      float hv = ov * tanhf(c_reg);
      hOutLds[rb_batch][rb_j] = (short)f2bf(hv);
      if (t == SS - 1) {
        int hcg = blk * 4 + rb_j;
        out[(size_t)BB * SS * HH + rb_batch * 1024 + hcg] = hv;            // h_f fp32
        out[(size_t)BB * SS * HH + 65536 + rb_batch * 1024 + hcg] = c_reg; // c_f fp32
      }
    }
    __syncthreads();

    // ---- phase C: flush h_{t+1} ----
    if (tid < 64) {
      unsigned long long v = *(const unsigned long long*)&hOutLds[tid][0];
      __hip_atomic_store(
          (unsigned long long*)(hseq + (size_t)(t + 1) * 65536 + tid * 1024 + blk * 4),
          v, __ATOMIC_RELAXED, __HIP_MEMORY_SCOPE_AGENT);
    }
    __syncthreads();

    // ---- phase D: barrier only ----
    if (t + 1 < SS) {
      if (tid == 256) { hbar_arrive(cnt, blk, t + 2); hbar_spin(cnt, t + 2); }
      __syncthreads();
    }
  }
}

// ---------------------------------------------------------------------------
// DIAGNOSTIC: sync-skeleton probe. The full per-step synchronization
// structure (4 syncthreads + 8B agent h-store + drain + hbar arrive/spin),
// NO GEMM loads / MFMA / gate math. 8192 iterations (16x a real run) so it
// is the slowest dispatch and lands top-1 in the rocprof table.
// per-step skeleton cost = dur_us / 8192.
// Writes into the xb region (rewritten by conv_x at each launch -> harmless).
// ---------------------------------------------------------------------------
__global__ void __launch_bounds__(512, 1) bar_probe(
    unsigned short* __restrict__ dummy,   // xb region (64 MB), rotating stores
    int* __restrict__ cnt)                // probe counter lines (own region)
{
  const int tid = threadIdx.x;
  const int blk = blockIdx.x;
  __syncthreads();
  for (int t = 0; t < 8192; ++t) {
    __syncthreads();                       // S1 (stand-in: end of GEMM phase)
    __syncthreads();                       // S2 (stand-in: end of gate phase)
    if (tid < 64) {
      unsigned long long w = (unsigned long long)(t ^ blk);
      __hip_atomic_store(
          (unsigned long long*)(dummy + (size_t)(t & 511) * 65536 + tid * 1024 + blk * 4),
          w, __ATOMIC_RELAXED, __HIP_MEMORY_SCOPE_AGENT);
    }
    __syncthreads();                       // S3: store drained
    if (tid == 256) { hbar_arrive(cnt, blk, t + 1); hbar_spin(cnt, t + 1); }
    __syncthreads();                       // S4: release
  }
}

// ---------------------------------------------------------------------------
// LEGACY fallback (cg::grid.sync) for small ws_size. Unchanged.
// ---------------------------------------------------------------------------
__global__ void __launch_bounds__(256) pack_w(
    const float* __restrict__ wii, const float* __restrict__ whi_,
    const float* __restrict__ wif, const float* __restrict__ whf,
    const float* __restrict__ wig, const float* __restrict__ whg,
    const float* __restrict__ wio, const float* __restrict__ who,
    unsigned short* __restrict__ Whi, unsigned short* __restrict__ Wlo)
{
  size_t idx = ((size_t)blockIdx.x * 256 + threadIdx.x) * 4;
  int k   = (int)(idx & 2047);
  int rg  = (int)(idx >> 11);
  int row = rg & 15;
  int blk = rg >> 4;
  int hc  = blk * 4 + (row >> 2);
  int g   = row & 3;
  const float* wi4[4] = {wii, wif, wig, wio};
  const float* wh4[4] = {whi_, whf, whg, who};
  const float* src = (k < 1024) ? (wi4[g] + (size_t)hc * 1024 + k)
                                : (wh4[g] + (size_t)hc * 1024 + (k - 1024));
  float4 v = *(const float4*)src;
  float vv[4] = {v.x, v.y, v.z, v.w};
  unsigned short h_[4], l_[4];
#pragma unroll
  for (int j = 0; j < 4; ++j) {
    unsigned short h = f2bf(vv[j]);
    h_[j] = h;
    l_[j] = f2bf(vv[j] - bf2f(h));
  }
  *(ushort4*)(Whi + idx) = make_ushort4(h_[0], h_[1], h_[2], h_[3]);
  *(ushort4*)(Wlo + idx) = make_ushort4(l_[0], l_[1], l_[2], l_[3]);
}

__global__ void __launch_bounds__(512, 1) lstm_seq_legacy(
    const unsigned short* __restrict__ W,
    const float* __restrict__ biasC,
    const float* __restrict__ xin,
    unsigned short* __restrict__ hb,
    const float* __restrict__ h0,
    const float* __restrict__ c0,
    float* __restrict__ out)
{
  __shared__ short Wl[2][16][2048];
  __shared__ float gLds[2][64][17];
  __shared__ float biasLds[16];

  const int tid  = threadIdx.x;
  const int blk  = blockIdx.x;
  const int wave = tid >> 6;
  const int lane = tid & 63;
  const int m    = wave >> 1;
  const int ks   = wave & 1;
  const int arow = m * 16 + (lane & 15);
  const int koff = (lane >> 4) * 8;
  const int brow = lane & 15;
  const int bswz = (brow & 7) << 4;

  {
    const char* srcH = (const char*)W + (size_t)blk * 65536;
    const char* srcL = (const char*)W + 16777216u + (size_t)blk * 65536;
    char* dstH = (char*)&Wl[0][0][0];
    char* dstL = (char*)&Wl[1][0][0];
#pragma unroll
    for (int it = 0; it < 8; ++it) {
      int boff = it * 8192 + tid * 16;
      int row  = boff >> 12;
      int colb = boff & 4095;
      int dsw  = row * 4096 + (colb ^ ((row & 7) << 4));
      *(int4*)(dstH + dsw) = *(const int4*)(srcH + boff);
      *(int4*)(dstL + dsw) = *(const int4*)(srcL + boff);
    }
  }
  if (tid < 16) biasLds[tid] = biasC[blk * 16 + tid];
  if (tid < 256) {
    int e = blk * 256 + tid;
    hb[e] = f2bf(h0[e]);
  }
  const int rb_batch = tid >> 2, rb_j = tid & 3;
  float c_reg = 0.f;
  if (tid < 256) c_reg = c0[rb_batch * 1024 + blk * 4 + rb_j];

  cg::grid_group grid = cg::this_grid();
  __syncthreads();
  grid.sync();

  const char* wrow = (const char*)&Wl[0][0][0] + brow * 4096;
  const int kbyte = ks * 2048;

  for (int t = 0; t < SS; ++t) {
    const unsigned short* hcur = hb + (t & 1) * 65536;
    f32x4 accH = {0.f, 0.f, 0.f, 0.f};
    f32x4 accL = {0.f, 0.f, 0.f, 0.f};

    if (ks == 1) {
      const unsigned short* aptr = hcur + arow * 1024 + koff;
#pragma unroll
      for (int kk = 0; kk < 1024; kk += 32) {
        s16x8 a = *(const s16x8*)(aptr + kk);
        int cb = (kbyte + (kk + koff) * 2) ^ bswz;
        s16x8 bh = *(const s16x8*)(wrow + cb);
        s16x8 bl = *(const s16x8*)(wrow + 65536 + cb);
        accH = __builtin_amdgcn_mfma_f32_16x16x32_bf16(a, bh, accH, 0, 0, 0);
        accL = __builtin_amdgcn_mfma_f32_16x16x32_bf16(a, bl, accL, 0, 0, 0);
      }
    } else {
      const float* xp = xin + ((size_t)arow * 512 + t) * 1024 + koff;
#pragma unroll
      for (int kk = 0; kk < 1024; kk += 32) {
        float4 f0 = *(const float4*)(xp + kk);
        float4 f1 = *(const float4*)(xp + kk + 4);
        s16x8 a;
        a[0] = (short)f2bf(f0.x); a[1] = (short)f2bf(f0.y);
        a[2] = (short)f2bf(f0.z); a[3] = (short)f2bf(f0.w);
        a[4] = (short)f2bf(f1.x); a[5] = (short)f2bf(f1.y);
        a[6] = (short)f2bf(f1.z); a[7] = (short)f2bf(f1.w);
        int cb = ((kk + koff) * 2) ^ bswz;
        s16x8 bh = *(const s16x8*)(wrow + cb);
        s16x8 bl = *(const s16x8*)(wrow + 65536 + cb);
        accH = __builtin_amdgcn_mfma_f32_16x16x32_bf16(a, bh, accH, 0, 0, 0);
        accL = __builtin_amdgcn_mfma_f32_16x16x32_bf16(a, bl, accL, 0, 0, 0);
      }
    }

    {
      f32x4 acc = accH + accL;
      int drow = m * 16 + (lane >> 4) * 4;
      int dcol = lane & 15;
#pragma unroll
      for (int r = 0; r < 4; ++r) gLds[ks][drow + r][dcol] = acc[r];
    }
    __syncthreads();

    if (tid < 256) {
      int c0i = rb_j * 4;
      float si = gLds[0][rb_batch][c0i + 0] + gLds[1][rb_batch][c0i + 0] + biasLds[c0i + 0];
      float sf = gLds[0][rb_batch][c0i + 1] + gLds[1][rb_batch][c0i + 1] + biasLds[c0i + 1];
      float sg = gLds[0][rb_batch][c0i + 2] + gLds[1][rb_batch][c0i + 2] + biasLds[c0i + 2];
      float so = gLds[0][rb_batch][c0i + 3] + gLds[1][rb_batch][c0i + 3] + biasLds[c0i + 3];
      float iv = 1.f / (1.f + __expf(-si));
      float fv = 1.f / (1.f + __expf(-sf));
      float gv = tanhf(sg);
      float ov = 1.f / (1.f + __expf(-so));
      c_reg = fv * c_reg + iv * gv;
      float hv = ov * tanhf(c_reg);
      int hcg = blk * 4 + rb_j;
      out[(size_t)rb_batch * (SS * HH) + (size_t)t * HH + hcg] = hv;
      hb[((t + 1) & 1) * 65536 + rb_batch * 1024 + hcg] = f2bf(hv);
      if (t == SS - 1) {
        out[(size_t)BB * SS * HH + rb_batch * 1024 + hcg] = hv;
        out[(size_t)BB * SS * HH + 65536 + rb_batch * 1024 + hcg] = c_reg;
      }
    }
    grid.sync();
  }
}

extern "C" void kernel_launch(void* const* d_in, const int* in_sizes, int n_in,
                              void* d_out, int out_size, void* d_ws, size_t ws_size,
                              hipStream_t stream) {
  const float* xin = (const float*)d_in[0];
  const float* h0  = (const float*)d_in[1];
  const float* c0  = (const float*)d_in[2];
  const float* wii = (const float*)d_in[3];
  const float* whi = (const float*)d_in[4];
  const float* bii = (const float*)d_in[5];
  const float* bhi = (const float*)d_in[6];
  const float* wif = (const float*)d_in[7];
  const float* whf = (const float*)d_in[8];
  const float* bif = (const float*)d_in[9];
  const float* bhf = (const float*)d_in[10];
  const float* wig = (const float*)d_in[11];
  const float* whg = (const float*)d_in[12];
  const float* big = (const float*)d_in[13];
  const float* bhg = (const float*)d_in[14];
  const float* wio = (const float*)d_in[15];
  const float* who = (const float*)d_in[16];
  const float* bio = (const float*)d_in[17];
  const float* bho = (const float*)d_in[18];
  float* out = (float*)d_out;

  char* ws = (char*)d_ws;
  // fast layout (byte-identical to proven r2-r6 layout)
  unsigned short* Wpk   = (unsigned short*)ws;                 // 32 MB
  float*          biasC = (float*)(ws + 33554432);             // 16 KB
  int*            cnt   = (int*)(ws + 33570816);               // 64 KB slot
  int*            cntP  = (int*)(ws + 33570816 + 4096);        // probe counters
  unsigned short* hseq  = (unsigned short*)(ws + 33636352);    // 513*131072
  unsigned short* xb    = (unsigned short*)(ws + 100876288);   // 64 MB
  const size_t need_fast    = 100876288ull;
  const size_t need_fast_xb = 100876288ull + 67108864ull;      // 167985152

  // legacy layout
  unsigned short* Wl_  = (unsigned short*)ws;                  // 32 MB hi+lo
  unsigned short* hb   = (unsigned short*)(ws + 33570816);     // 256 KB

  if (ws_size >= need_fast) {
    const bool use_xb = ws_size >= need_fast_xb;
    pack_w_lin<<<8192, 256, 0, stream>>>(wii, whi, wif, whf, wig, whg, wio, who, Wpk);
    pack_bias<<<16, 256, 0, stream>>>(bii, bhi, bif, bhf, big, bhg, bio, bho, biasC);
    if (use_xb) conv_x<<<32768, 256, 0, stream>>>(xin, xb);
    hipMemsetAsync(cnt, 0, 16384, stream);

    void* ka[] = {(void*)&Wpk, (void*)&biasC, (void*)&xb, (void*)&xin,
                  (void*)&hseq, (void*)&cnt, (void*)&h0, (void*)&c0, (void*)&out};
    if (use_xb) {
      hipLaunchCooperativeKernel(reinterpret_cast<const void*>(&lstm_fast3<true>),
                                 dim3(256), dim3(512), ka, 0, stream);
    } else {
      hipLaunchCooperativeKernel(reinterpret_cast<const void*>(&lstm_fast3<false>),
                                 dim3(256), dim3(512), ka, 0, stream);
    }
    conv_out<<<32768, 256, 0, stream>>>(hseq, out);

    // ---- diagnostic probe (writes only xb scratch; xb is regenerated by
    //      conv_x at the start of every launch/replay) ----
    if (use_xb) {
      void* kp[] = {(void*)&xb, (void*)&cntP};
      hipLaunchCooperativeKernel(reinterpret_cast<const void*>(&bar_probe),
                                 dim3(256), dim3(512), kp, 0, stream);
    }
  } else {
    pack_w<<<8192, 256, 0, stream>>>(wii, whi, wif, whf, wig, whg, wio, who,
                                     Wl_, Wl_ + 8388608);
    pack_bias<<<16, 256, 0, stream>>>(bii, bhi, bif, bhf, big, bhg, bio, bho, biasC);
    void* ka[] = {(void*)&Wl_, (void*)&biasC, (void*)&xin,
                  (void*)&hb, (void*)&h0, (void*)&c0, (void*)&out};
    hipLaunchCooperativeKernel(reinterpret_cast<const void*>(&lstm_seq_legacy),
                               dim3(256), dim3(512), ka, 0, stream);
  }
}

// Round 8
// 4432.359 us; speedup vs baseline: 5.8440x; 5.8440x over previous
//
#include <hip/hip_runtime.h>
#include <hip/hip_bf16.h>
#include <hip/hip_cooperative_groups.h>

namespace cg = cooperative_groups;

using s16x8 = __attribute__((ext_vector_type(8))) short;   // 8 bf16 (4 VGPRs) MFMA frag
using f32x4 = __attribute__((ext_vector_type(4))) float;   // MFMA accumulator

constexpr int BB = 64;    // batch
constexpr int SS = 512;   // seq len
constexpr int II = 1024;  // input dim
constexpr int HH = 1024;  // hidden dim

__device__ __forceinline__ unsigned short f2bf(float f) {
  unsigned u = __float_as_uint(f);
  unsigned r = u + 0x7fffu + ((u >> 16) & 1u);   // RN-even
  return (unsigned short)(r >> 16);
}
__device__ __forceinline__ float bf2f(unsigned short h) {
  return __uint_as_float(((unsigned)h) << 16);
}

// ---------------------------------------------------------------------------
// W in MFMA-linear fragment order: Wpk[blk 256][hl 2][ks 2][kb 32][lane 64][e 8]
// ---------------------------------------------------------------------------
__global__ void __launch_bounds__(256) pack_w_lin(
    const float* __restrict__ wii, const float* __restrict__ whi_,
    const float* __restrict__ wif, const float* __restrict__ whf,
    const float* __restrict__ wig, const float* __restrict__ whg,
    const float* __restrict__ wio, const float* __restrict__ who,
    unsigned short* __restrict__ Wpk)
{
  unsigned f = blockIdx.x * 256 + threadIdx.x;   // frag id, 0..2097151
  int lane = f & 63;
  int kb   = (f >> 6) & 31;
  int ks   = (f >> 11) & 1;
  int hl   = (f >> 12) & 1;
  int blk  = (int)(f >> 13);
  int n = lane & 15, u = lane >> 4;
  int hc = blk * 4 + (n >> 2), g = n & 3;
  int k  = kb * 32 + u * 8;
  const float* wi4[4] = {wii, wif, wig, wio};
  const float* wh4[4] = {whi_, whf, whg, who};
  const float* src = (ks == 0) ? (wi4[g] + (size_t)hc * 1024 + k)
                               : (wh4[g] + (size_t)hc * 1024 + k);
  float4 v0 = *(const float4*)src;
  float4 v1 = *(const float4*)(src + 4);
  float vv[8] = {v0.x, v0.y, v0.z, v0.w, v1.x, v1.y, v1.z, v1.w};
  s16x8 r;
#pragma unroll
  for (int e = 0; e < 8; ++e) {
    unsigned short h = f2bf(vv[e]);
    r[e] = hl ? (short)f2bf(vv[e] - bf2f(h))   // residual split removes W-quant err
              : (short)h;
  }
  *(s16x8*)(Wpk + (size_t)f * 8) = r;
}

__global__ void __launch_bounds__(256) pack_bias(
    const float* __restrict__ bii, const float* __restrict__ bhi,
    const float* __restrict__ bif, const float* __restrict__ bhf,
    const float* __restrict__ big, const float* __restrict__ bhg,
    const float* __restrict__ bio, const float* __restrict__ bho,
    float* __restrict__ biasC)
{
  int cidx = blockIdx.x * 256 + threadIdx.x;  // 0..4095
  int col = cidx & 15, blk = cidx >> 4;
  int hc = blk * 4 + (col >> 2), g = col & 3;
  const float* bi4[4] = {bii, bif, big, bio};
  const float* bh4[4] = {bhi, bhf, bhg, bho};
  biasC[cidx] = bi4[g][hc] + bh4[g][hc];
}

// x [B][S][I] fp32 -> xb [S][B][I] bf16
__global__ void __launch_bounds__(256) conv_x(const float* __restrict__ x,
                                              unsigned short* __restrict__ xb)
{
  int bs = blockIdx.x;
  int b = bs >> 9, s = bs & 511;
  float4 v = *(const float4*)(x + ((size_t)b * 512 + s) * 1024 + threadIdx.x * 4);
  *(ushort4*)(xb + ((size_t)s * 64 + b) * 1024 + threadIdx.x * 4) =
      make_ushort4(f2bf(v.x), f2bf(v.y), f2bf(v.z), f2bf(v.w));
}

// hseq [S+1][B][H] bf16 -> out hidden_seq [B][S][H] fp32
__global__ void __launch_bounds__(256) conv_out(const unsigned short* __restrict__ hseq,
                                                float* __restrict__ out)
{
  int bt = blockIdx.x;             // 0..32767
  int b = bt >> 9, t = bt & 511;
  ushort4 v = *(const ushort4*)(hseq + (size_t)(t + 1) * 65536 + b * 1024 + threadIdx.x * 4);
  float4 o;
  o.x = bf2f(v.x); o.y = bf2f(v.y); o.z = bf2f(v.z); o.w = bf2f(v.w);
  *(float4*)(out + ((size_t)b * 512 + t) * 1024 + threadIdx.x * 4) = o;
}

// ---------------------------------------------------------------------------
// Hierarchical monotone barrier (r4, probe-measured inside 2.45us skeleton).
// ---------------------------------------------------------------------------
__device__ __forceinline__ void hbar_arrive(int* cnt, int blk, int kbar) {
  int g = blk & 7;
  int* lp = cnt + g * 16;
  __hip_atomic_fetch_add(lp, 1, __ATOMIC_RELAXED, __HIP_MEMORY_SCOPE_AGENT);
  if (blk < 8) {   // master of group g == blk
    while (__hip_atomic_load(lp, __ATOMIC_RELAXED, __HIP_MEMORY_SCOPE_AGENT) < 32 * kbar)
      __builtin_amdgcn_s_sleep(1);
    __hip_atomic_fetch_add(cnt + 8 * 16, 1, __ATOMIC_RELAXED, __HIP_MEMORY_SCOPE_AGENT);
  }
}
__device__ __forceinline__ void hbar_spin(int* cnt, int kbar) {
  int* gp = cnt + 8 * 16;
  while (__hip_atomic_load(gp, __ATOMIC_RELAXED, __HIP_MEMORY_SCOPE_AGENT) < 8 * kbar)
    __builtin_amdgcn_s_sleep(1);
}

// ---------------------------------------------------------------------------
// K-split bf16 GEMM quarter: 16 frag loads (16 KB/wave), 32 MFMAs (hi+lo).
// Half the serial load chain of the old 32-frag version; run on all 8 waves
// concurrently -> 2x memory-level parallelism on the critical h-phase.
// ---------------------------------------------------------------------------
__device__ __forceinline__ void gemm_half(const unsigned short* __restrict__ aptr,
                                          const s16x8* __restrict__ WlV, int wb,
                                          f32x4& outH, f32x4& outL) {
  s16x8 a[16];
#pragma unroll
  for (int kb = 0; kb < 16; ++kb) a[kb] = *(const s16x8*)(aptr + kb * 32);
  f32x4 h0 = {0.f, 0.f, 0.f, 0.f}, h1 = h0, l0 = h0, l1 = h0;
#pragma unroll
  for (int kb = 0; kb < 16; kb += 2) {
    s16x8 bh0 = WlV[wb + kb * 64];
    s16x8 bl0 = WlV[4096 + wb + kb * 64];
    s16x8 bh1 = WlV[wb + (kb + 1) * 64];
    s16x8 bl1 = WlV[4096 + wb + (kb + 1) * 64];
    h0 = __builtin_amdgcn_mfma_f32_16x16x32_bf16(a[kb],     bh0, h0, 0, 0, 0);
    l0 = __builtin_amdgcn_mfma_f32_16x16x32_bf16(a[kb],     bl0, l0, 0, 0, 0);
    h1 = __builtin_amdgcn_mfma_f32_16x16x32_bf16(a[kb + 1], bh1, h1, 0, 0, 0);
    l1 = __builtin_amdgcn_mfma_f32_16x16x32_bf16(a[kb + 1], bl1, l1, 0, 0, 0);
  }
  outH = h0 + h1;
  outL = l0 + l1;
}

// ---------------------------------------------------------------------------
// Persistent LSTM v7. 256 blocks x 512 threads, 1 block/CU.
// Wave w: m = w&3 (batch 16-row tile), kh = w>>2 (K-half 512).
// A: all 8 waves publish xacc(t) partial, then K-split h-GEMM(t).     -> S1
// B: gate math sums 4 partials (gX[0..1], gH[0..1]) + bias.           -> S2
// C: flush h_{t+1} (64 x 8B agent stores).                            -> S3
// D: arrive; all 8 waves K-split x-GEMM(t+1) under the wait; spin.    -> S4
// ---------------------------------------------------------------------------
__global__ void __launch_bounds__(512, 1) lstm_fast6(
    const unsigned short* __restrict__ Wpk,  // [256][2][2][32][64][8] bf16
    const float* __restrict__ biasC,         // [256][16]
    const unsigned short* __restrict__ xb,   // [S][B][I] bf16
    unsigned short* __restrict__ hseq,       // [S+1][B][H] bf16 rotating
    int* __restrict__ cnt,                   // 9 lines x 64B, monotone
    const float* __restrict__ h0,
    const float* __restrict__ c0,
    float* __restrict__ out)                 // [hidden_seq][h_f][c_f]
{
  __shared__ s16x8 WlV[8192];                // 128 KB, MFMA-linear frags
  __shared__ float gX[2][64][17];            // x partials per K-half
  __shared__ float gH[2][64][17];            // h partials per K-half
  __shared__ float biasLds[16];
  __shared__ short hOutLds[64][4];           // staged h_{t+1} for 8B flush

  const int tid  = threadIdx.x;
  const int blk  = blockIdx.x;
  const int wave = tid >> 6, lane = tid & 63;
  const int m  = wave & 3;        // batch tile
  const int kh = wave >> 2;       // K-half within each operand
  const int arow = m * 16 + (lane & 15);
  const int koff = (lane >> 4) * 8;
  const int aoff = arow * 1024 + kh * 512 + koff;   // element offset in a t-slot
  const int wbX = kh * 1024 + lane;                 // W frag base, x-part K-half
  const int wbH = 2048 + kh * 1024 + lane;          // W frag base, h-part K-half
  const int drow = m * 16 + (lane >> 4) * 4;
  const int dcol = lane & 15;

  // stage this block's W chunk (linear 128 KB copy; frag order == read order)
  {
    const s16x8* src = (const s16x8*)(Wpk + (size_t)blk * 65536);
#pragma unroll
    for (int it = 0; it < 16; ++it) WlV[it * 512 + tid] = src[it * 512 + tid];
  }
  if (tid < 16) biasLds[tid] = biasC[blk * 16 + tid];

  // init hseq slot 0 from h0 with agent-visible stores
  if (tid < 128) {
    int p = blk * 128 + tid;                 // pair index over B*H/2
    unsigned lo = f2bf(h0[2 * p]), hi = f2bf(h0[2 * p + 1]);
    __hip_atomic_store((unsigned*)(hseq + 2 * p), lo | (hi << 16),
                       __ATOMIC_RELAXED, __HIP_MEMORY_SCOPE_AGENT);
  }
  const int rb_batch = tid >> 2, rb_j = tid & 3;
  float c_reg = 0.f;
  if (tid < 256) c_reg = c0[rb_batch * 1024 + blk * 4 + rb_j];

  __syncthreads();                           // W staged; h0 stores drained

  // prologue: x-GEMM(0) on all 8 waves (K-split)
  f32x4 xaccH = {0.f, 0.f, 0.f, 0.f}, xaccL = xaccH;
  gemm_half(xb + aoff, WlV, wbX, xaccH, xaccL);

  if (tid == 256) { hbar_arrive(cnt, blk, 1); hbar_spin(cnt, 1); }
  __syncthreads();                           // hseq slot 0 globally visible

  for (int t = 0; t < SS; ++t) {
    // ---- phase A: publish xacc(t); K-split h-GEMM(t); publish h partials ----
    {
      f32x4 xs = xaccH + xaccL;
#pragma unroll
      for (int r = 0; r < 4; ++r) gX[kh][drow + r][dcol] = xs[r];
    }
    {
      f32x4 pH, pL;
      gemm_half(hseq + (size_t)t * 65536 + aoff, WlV, wbH, pH, pL);
      f32x4 hs = pH + pL;
#pragma unroll
      for (int r = 0; r < 4; ++r) gH[kh][drow + r][dcol] = hs[r];
    }
    __syncthreads();                         // S1

    // ---- phase B: gate math over 4 partials ----
    if (tid < 256) {
      int c0i = rb_j * 4;
      float si = gX[0][rb_batch][c0i + 0] + gX[1][rb_batch][c0i + 0]
               + gH[0][rb_batch][c0i + 0] + gH[1][rb_batch][c0i + 0] + biasLds[c0i + 0];
      float sf = gX[0][rb_batch][c0i + 1] + gX[1][rb_batch][c0i + 1]
               + gH[0][rb_batch][c0i + 1] + gH[1][rb_batch][c0i + 1] + biasLds[c0i + 1];
      float sg = gX[0][rb_batch][c0i + 2] + gX[1][rb_batch][c0i + 2]
               + gH[0][rb_batch][c0i + 2] + gH[1][rb_batch][c0i + 2] + biasLds[c0i + 2];
      float so = gX[0][rb_batch][c0i + 3] + gX[1][rb_batch][c0i + 3]
               + gH[0][rb_batch][c0i + 3] + gH[1][rb_batch][c0i + 3] + biasLds[c0i + 3];
      float iv = 1.f / (1.f + __expf(-si));
      float fv = 1.f / (1.f + __expf(-sf));
      float gv = tanhf(sg);
      float ov = 1.f / (1.f + __expf(-so));
      c_reg = fv * c_reg + iv * gv;
      float hv = ov * tanhf(c_reg);
      hOutLds[rb_batch][rb_j] = (short)f2bf(hv);
      if (t == SS - 1) {
        int hcg = blk * 4 + rb_j;
        out[(size_t)BB * SS * HH + rb_batch * 1024 + hcg] = hv;            // h_f fp32
        out[(size_t)BB * SS * HH + 65536 + rb_batch * 1024 + hcg] = c_reg; // c_f fp32
      }
    }
    __syncthreads();                         // S2

    // ---- phase C: flush h_{t+1} (64 x 8B agent stores) ----
    if (tid < 64) {
      unsigned long long v = *(const unsigned long long*)&hOutLds[tid][0];
      __hip_atomic_store(
          (unsigned long long*)(hseq + (size_t)(t + 1) * 65536 + tid * 1024 + blk * 4),
          v, __ATOMIC_RELAXED, __HIP_MEMORY_SCOPE_AGENT);
    }
    __syncthreads();                         // S3: flush drained per thread

    // ---- phase D: arrive; x-GEMM(t+1) on all 8 waves under the wait; spin ----
    if (t + 1 < SS) {
      if (tid == 256) hbar_arrive(cnt, blk, t + 2);
      gemm_half(xb + (size_t)(t + 1) * 65536 + aoff, WlV, wbX, xaccH, xaccL);
      if (tid == 256) hbar_spin(cnt, t + 2);
      __syncthreads();                       // S4: h_{t+1} globally visible
    }
  }
}

// ---------------------------------------------------------------------------
// LEGACY fallback (cg::grid.sync) for small ws_size. Unchanged.
// ---------------------------------------------------------------------------
__global__ void __launch_bounds__(256) pack_w(
    const float* __restrict__ wii, const float* __restrict__ whi_,
    const float* __restrict__ wif, const float* __restrict__ whf,
    const float* __restrict__ wig, const float* __restrict__ whg,
    const float* __restrict__ wio, const float* __restrict__ who,
    unsigned short* __restrict__ Whi, unsigned short* __restrict__ Wlo)
{
  size_t idx = ((size_t)blockIdx.x * 256 + threadIdx.x) * 4;
  int k   = (int)(idx & 2047);
  int rg  = (int)(idx >> 11);
  int row = rg & 15;
  int blk = rg >> 4;
  int hc  = blk * 4 + (row >> 2);
  int g   = row & 3;
  const float* wi4[4] = {wii, wif, wig, wio};
  const float* wh4[4] = {whi_, whf, whg, who};
  const float* src = (k < 1024) ? (wi4[g] + (size_t)hc * 1024 + k)
                                : (wh4[g] + (size_t)hc * 1024 + (k - 1024));
  float4 v = *(const float4*)src;
  float vv[4] = {v.x, v.y, v.z, v.w};
  unsigned short h_[4], l_[4];
#pragma unroll
  for (int j = 0; j < 4; ++j) {
    unsigned short h = f2bf(vv[j]);
    h_[j] = h;
    l_[j] = f2bf(vv[j] - bf2f(h));
  }
  *(ushort4*)(Whi + idx) = make_ushort4(h_[0], h_[1], h_[2], h_[3]);
  *(ushort4*)(Wlo + idx) = make_ushort4(l_[0], l_[1], l_[2], l_[3]);
}

__global__ void __launch_bounds__(512, 1) lstm_seq_legacy(
    const unsigned short* __restrict__ W,
    const float* __restrict__ biasC,
    const float* __restrict__ xin,
    unsigned short* __restrict__ hb,
    const float* __restrict__ h0,
    const float* __restrict__ c0,
    float* __restrict__ out)
{
  __shared__ short Wl[2][16][2048];
  __shared__ float gLds[2][64][17];
  __shared__ float biasLds[16];

  const int tid  = threadIdx.x;
  const int blk  = blockIdx.x;
  const int wave = tid >> 6;
  const int lane = tid & 63;
  const int m    = wave >> 1;
  const int ks   = wave & 1;
  const int arow = m * 16 + (lane & 15);
  const int koff = (lane >> 4) * 8;
  const int brow = lane & 15;
  const int bswz = (brow & 7) << 4;

  {
    const char* srcH = (const char*)W + (size_t)blk * 65536;
    const char* srcL = (const char*)W + 16777216u + (size_t)blk * 65536;
    char* dstH = (char*)&Wl[0][0][0];
    char* dstL = (char*)&Wl[1][0][0];
#pragma unroll
    for (int it = 0; it < 8; ++it) {
      int boff = it * 8192 + tid * 16;
      int row  = boff >> 12;
      int colb = boff & 4095;
      int dsw  = row * 4096 + (colb ^ ((row & 7) << 4));
      *(int4*)(dstH + dsw) = *(const int4*)(srcH + boff);
      *(int4*)(dstL + dsw) = *(const int4*)(srcL + boff);
    }
  }
  if (tid < 16) biasLds[tid] = biasC[blk * 16 + tid];
  if (tid < 256) {
    int e = blk * 256 + tid;
    hb[e] = f2bf(h0[e]);
  }
  const int rb_batch = tid >> 2, rb_j = tid & 3;
  float c_reg = 0.f;
  if (tid < 256) c_reg = c0[rb_batch * 1024 + blk * 4 + rb_j];

  cg::grid_group grid = cg::this_grid();
  __syncthreads();
  grid.sync();

  const char* wrow = (const char*)&Wl[0][0][0] + brow * 4096;
  const int kbyte = ks * 2048;

  for (int t = 0; t < SS; ++t) {
    const unsigned short* hcur = hb + (t & 1) * 65536;
    f32x4 accH = {0.f, 0.f, 0.f, 0.f};
    f32x4 accL = {0.f, 0.f, 0.f, 0.f};

    if (ks == 1) {
      const unsigned short* aptr = hcur + arow * 1024 + koff;
#pragma unroll
      for (int kk = 0; kk < 1024; kk += 32) {
        s16x8 a = *(const s16x8*)(aptr + kk);
        int cb = (kbyte + (kk + koff) * 2) ^ bswz;
        s16x8 bh = *(const s16x8*)(wrow + cb);
        s16x8 bl = *(const s16x8*)(wrow + 65536 + cb);
        accH = __builtin_amdgcn_mfma_f32_16x16x32_bf16(a, bh, accH, 0, 0, 0);
        accL = __builtin_amdgcn_mfma_f32_16x16x32_bf16(a, bl, accL, 0, 0, 0);
      }
    } else {
      const float* xp = xin + ((size_t)arow * 512 + t) * 1024 + koff;
#pragma unroll
      for (int kk = 0; kk < 1024; kk += 32) {
        float4 f0 = *(const float4*)(xp + kk);
        float4 f1 = *(const float4*)(xp + kk + 4);
        s16x8 a;
        a[0] = (short)f2bf(f0.x); a[1] = (short)f2bf(f0.y);
        a[2] = (short)f2bf(f0.z); a[3] = (short)f2bf(f0.w);
        a[4] = (short)f2bf(f1.x); a[5] = (short)f2bf(f1.y);
        a[6] = (short)f2bf(f1.z); a[7] = (short)f2bf(f1.w);
        int cb = ((kk + koff) * 2) ^ bswz;
        s16x8 bh = *(const s16x8*)(wrow + cb);
        s16x8 bl = *(const s16x8*)(wrow + 65536 + cb);
        accH = __builtin_amdgcn_mfma_f32_16x16x32_bf16(a, bh, accH, 0, 0, 0);
        accL = __builtin_amdgcn_mfma_f32_16x16x32_bf16(a, bl, accL, 0, 0, 0);
      }
    }

    {
      f32x4 acc = accH + accL;
      int drow = m * 16 + (lane >> 4) * 4;
      int dcol = lane & 15;
#pragma unroll
      for (int r = 0; r < 4; ++r) gLds[ks][drow + r][dcol] = acc[r];
    }
    __syncthreads();

    if (tid < 256) {
      int c0i = rb_j * 4;
      float si = gLds[0][rb_batch][c0i + 0] + gLds[1][rb_batch][c0i + 0] + biasLds[c0i + 0];
      float sf = gLds[0][rb_batch][c0i + 1] + gLds[1][rb_batch][c0i + 1] + biasLds[c0i + 1];
      float sg = gLds[0][rb_batch][c0i + 2] + gLds[1][rb_batch][c0i + 2] + biasLds[c0i + 2];
      float so = gLds[0][rb_batch][c0i + 3] + gLds[1][rb_batch][c0i + 3] + biasLds[c0i + 3];
      float iv = 1.f / (1.f + __expf(-si));
      float fv = 1.f / (1.f + __expf(-sf));
      float gv = tanhf(sg);
      float ov = 1.f / (1.f + __expf(-so));
      c_reg = fv * c_reg + iv * gv;
      float hv = ov * tanhf(c_reg);
      int hcg = blk * 4 + rb_j;
      out[(size_t)rb_batch * (SS * HH) + (size_t)t * HH + hcg] = hv;
      hb[((t + 1) & 1) * 65536 + rb_batch * 1024 + hcg] = f2bf(hv);
      if (t == SS - 1) {
        out[(size_t)BB * SS * HH + rb_batch * 1024 + hcg] = hv;
        out[(size_t)BB * SS * HH + 65536 + rb_batch * 1024 + hcg] = c_reg;
      }
    }
    grid.sync();
  }
}

extern "C" void kernel_launch(void* const* d_in, const int* in_sizes, int n_in,
                              void* d_out, int out_size, void* d_ws, size_t ws_size,
                              hipStream_t stream) {
  const float* xin = (const float*)d_in[0];
  const float* h0  = (const float*)d_in[1];
  const float* c0  = (const float*)d_in[2];
  const float* wii = (const float*)d_in[3];
  const float* whi = (const float*)d_in[4];
  const float* bii = (const float*)d_in[5];
  const float* bhi = (const float*)d_in[6];
  const float* wif = (const float*)d_in[7];
  const float* whf = (const float*)d_in[8];
  const float* bif = (const float*)d_in[9];
  const float* bhf = (const float*)d_in[10];
  const float* wig = (const float*)d_in[11];
  const float* whg = (const float*)d_in[12];
  const float* big = (const float*)d_in[13];
  const float* bhg = (const float*)d_in[14];
  const float* wio = (const float*)d_in[15];
  const float* who = (const float*)d_in[16];
  const float* bio = (const float*)d_in[17];
  const float* bho = (const float*)d_in[18];
  float* out = (float*)d_out;

  char* ws = (char*)d_ws;
  // fast layout (byte-identical to proven r2-r7 layout)
  unsigned short* Wpk   = (unsigned short*)ws;                 // 32 MB
  float*          biasC = (float*)(ws + 33554432);             // 16 KB
  int*            cnt   = (int*)(ws + 33570816);               // 64 KB slot (uses 576 B)
  unsigned short* hseq  = (unsigned short*)(ws + 33636352);    // 513*131072
  unsigned short* xb    = (unsigned short*)(ws + 100876288);   // 64 MB
  const size_t need_fast_xb = 100876288ull + 67108864ull;      // 167985152

  // legacy layout
  unsigned short* Wl_  = (unsigned short*)ws;                  // 32 MB hi+lo
  unsigned short* hb   = (unsigned short*)(ws + 33570816);     // 256 KB

  if (ws_size >= need_fast_xb) {
    pack_w_lin<<<8192, 256, 0, stream>>>(wii, whi, wif, whf, wig, whg, wio, who, Wpk);
    pack_bias<<<16, 256, 0, stream>>>(bii, bhi, bif, bhf, big, bhg, bio, bho, biasC);
    conv_x<<<32768, 256, 0, stream>>>(xin, xb);
    hipMemsetAsync(cnt, 0, 4096, stream);

    void* ka[] = {(void*)&Wpk, (void*)&biasC, (void*)&xb,
                  (void*)&hseq, (void*)&cnt, (void*)&h0, (void*)&c0, (void*)&out};
    hipLaunchCooperativeKernel(reinterpret_cast<const void*>(&lstm_fast6),
                               dim3(256), dim3(512), ka, 0, stream);
    conv_out<<<32768, 256, 0, stream>>>(hseq, out);
  } else {
    pack_w<<<8192, 256, 0, stream>>>(wii, whi, wif, whf, wig, whg, wio, who,
                                     Wl_, Wl_ + 8388608);
    pack_bias<<<16, 256, 0, stream>>>(bii, bhi, bif, bhf, big, bhg, bio, bho, biasC);
    void* ka[] = {(void*)&Wl_, (void*)&biasC, (void*)&xin,
                  (void*)&hb, (void*)&h0, (void*)&c0, (void*)&out};
    hipLaunchCooperativeKernel(reinterpret_cast<const void*>(&lstm_seq_legacy),
                               dim3(256), dim3(512), ka, 0, stream);
  }
}